// Round 10
// baseline (49.187 us; speedup 1.0000x reference)
//
#include <hip/hip_runtime.h>
#include <hip/hip_bf16.h>

#define NB 64
#define NS 1024
#define DD 256
#define NT 36          // upper-triangular 8x8 tile count
#define THR 120.0f     // dist^2 below which exp(-dist) can matter

typedef __attribute__((ext_vector_type(4))) float f32x4;
typedef __attribute__((ext_vector_type(8))) short bf16x8;
typedef __attribute__((ext_vector_type(8))) unsigned short u16x8;
typedef __attribute__((ext_vector_type(4))) unsigned short u16x4;

__device__ __forceinline__ unsigned short f2bf(float x) {
  union { float f; unsigned int u; } c; c.f = x;
  unsigned int r = c.u + 0x7fffu + ((c.u >> 16) & 1u);
  return (unsigned short)(r >> 16);
}

__device__ __forceinline__ float bf2f(unsigned short x) {
  union { unsigned int u; float f; } c; c.u = ((unsigned int)x) << 16;
  return c.f;
}

// dbf2 layout (kg-major fragment blocks): block(b, kg, rt) = (b*8 + kg)*64 + rt,
// 512 bf16 each. Slot s (0..63) holds 8 bf16: row = rt*16 + (s&15),
// k = kg*32 + (s>>4)*8 + 0..7.  A wave's MFMA fragment load is ONE coalesced
// 1KB global_load_dwordx4; prep's fragment STORE is likewise one coalesced
// 1KB store per kg (lane l -> slot l), via an LDS transpose.

// ---- prep: blocks [0,1024): one 16-row tile per wave. Phase A: 16 coalesced
//      1KB row loads, bf16 cvt, XOR-swizzled LDS write (conflict-free).
//      Phase B: swizzled ds_read_b128 -> 8 coalesced 1KB fragment stores,
//      fused sq accumulation from the fragments (lane covers row l&15,
//      k-quarter l>>4 -> TWO shfl_xor steps finish all 16 row-sums; replaces
//      the 96-shuffle-per-wave storm of R8). sq from bf16 is safe: sq only
//      reaches the output through the d2<THR kd path.
//      XCD-matched: XCD k (= px&7) writes batches [8k,8k+8) = main's readers.
//      blocks [1024,1536): denom2/C partials over W/S (no atomics). ----
__global__ __launch_bounds__(256) void prep_kernel(const float* __restrict__ din,
                                                   unsigned short* __restrict__ dbf2,
                                                   float* __restrict__ sq,
                                                   const float* __restrict__ S,
                                                   const float* __restrict__ W,
                                                   float* __restrict__ dpart,
                                                   float* __restrict__ cpart,
                                                   int write_bf) {
  const int px = (int)blockIdx.x;
  const int wid = (int)threadIdx.x >> 6;
  const int l = (int)threadIdx.x & 63;
  if (px < 1024) {
    __shared__ unsigned short lds[4][16][256];   // 4 waves x 8KB, wave-private
    unsigned short (*T)[256] = lds[wid];
    const int tb = (px & 7) * 128 + (px >> 3);
    const int task = tb * 4 + wid;               // b*64 + rt
    const int b = task >> 6, rt = task & 63;
    const float4* src =
        reinterpret_cast<const float4*>(din + ((size_t)b * NS + rt * 16) * DD) + l;
    if (write_bf) {
      // phase A: load + cvt + swizzled LDS write only (no per-row reduce)
      #pragma unroll
      for (int r16 = 0; r16 < 16; ++r16) {
        float4 v = src[r16 * 64];                // row stride 256 f = 64 float4
        u16x4 o;
        o[0] = f2bf(v.x); o[1] = f2bf(v.y); o[2] = f2bf(v.z); o[3] = f2bf(v.w);
        const int cp = (l >> 1) ^ (r16 & 7);
        *reinterpret_cast<u16x4*>(&T[r16][cp * 8 + (l & 1) * 4]) = o;
      }
      // phase B: 8 swizzled LDS reads -> 8 coalesced 1KB stores; fused sq.
      // lane l covers row (l&15), k = kg*32 + (l>>4)*8 + 0..7 over all kg.
      unsigned short* dst = dbf2 + (((size_t)b * 8) * 64 + rt) * 512 + (size_t)l * 8;
      float ssum = 0.f;
      #pragma unroll
      for (int kg = 0; kg < 8; ++kg) {
        const int cc = (kg * 4 + (l >> 4)) ^ (l & 7);
        u16x8 frag = *reinterpret_cast<const u16x8*>(&T[l & 15][cc * 8]);
        *reinterpret_cast<u16x8*>(dst + (size_t)kg * 64 * 512) = frag;
        #pragma unroll
        for (int e = 0; e < 8; ++e) {
          const float f = bf2f(frag[e]);
          ssum = fmaf(f, f, ssum);
        }
      }
      ssum += __shfl_xor(ssum, 16, 64);
      ssum += __shfl_xor(ssum, 32, 64);
      if (l < 16) sq[(size_t)b * NS + rt * 16 + l] = ssum;
    } else {
      // fallback (no workspace): exact f32 sq via per-row reduce
      #pragma unroll
      for (int r16 = 0; r16 < 16; ++r16) {
        float4 v = src[r16 * 64];
        float s = v.x * v.x + v.y * v.y + v.z * v.z + v.w * v.w;
        #pragma unroll
        for (int off = 32; off > 0; off >>= 1) s += __shfl_xor(s, off, 64);
        if (l == 0) sq[(size_t)b * NS + rt * 16 + r16] = s;
      }
    }
    return;
  }
  // denomC partials: blk in [0,512), 256 thr x 2 float4 each
  const int blk = px - 1024;
  const int base = blk * 256 + (int)threadIdx.x;
  float dsum = 0.f, csum = 0.f;
  #pragma unroll
  for (int rpt = 0; rpt < 2; ++rpt) {
    const int idx = base + rpt * 131072;
    float4 w = reinterpret_cast<const float4*>(W)[idx];
    float4 s4 = reinterpret_cast<const float4*>(S)[idx];
    const int e0 = idx << 2;
    const int r = e0 >> 10, c0 = e0 & 1023;
    float wv[4] = {w.x, w.y, w.z, w.w};
    float sv[4] = {s4.x, s4.y, s4.z, s4.w};
    #pragma unroll
    for (int i = 0; i < 4; ++i) {
      const bool dg = (c0 + i) == r;
      const float a = wv[i] - (dg ? 1.0f : 0.0f);
      dsum = fmaf(a, a, dsum);
      const float bq = dg ? (1.0f - sv[i]) : sv[i];
      csum = fmaf(wv[i] * bq, bq, csum);   // W binary: W^2 == W
    }
  }
  #pragma unroll
  for (int off = 32; off > 0; off >>= 1) {
    dsum += __shfl_xor(dsum, off, 64);
    csum += __shfl_xor(csum, off, 64);
  }
  __shared__ float redD[4], redC[4];
  if (l == 0) { redD[wid] = dsum; redC[wid] = csum; }
  __syncthreads();
  if (threadIdx.x == 0) {
    dpart[blk] = redD[0] + redD[1] + redD[2] + redD[3];
    cpart[blk] = redC[0] + redC[1] + redC[2] + redC[3];
  }
}

// ---- main: barrier-free LDS-free MFMA Gram; one batch per block (GB=1).
// Fragment loads hit the LOCAL XCD L2 (prep placement matched). Software
// prefetch distance 1. Per-(block,wave) partial output, no atomics.
template <int MODE>
__global__ __launch_bounds__(256, 2) void main_kernel(
    const float* __restrict__ dvec, const unsigned short* __restrict__ dbf2,
    const float* __restrict__ sq, const float* __restrict__ S,
    const float* __restrict__ W, float* __restrict__ npart) {
  const int tid = threadIdx.x;
  const int lane = tid & 63;
  const int wid = tid >> 6;
  const int wr = wid >> 1;
  const int wc = wid & 1;

  // XCD-chunked bijective swizzle (2304 = 8 * 288): XCD k gets bids
  // [288k, 288k+288) -> b in [8k, 8k+8) (t-fast) = the batches its L2 holds.
  const int orig = (int)blockIdx.x;
  const int bid = (orig & 7) * (NT * NB / 8) + (orig >> 3);
  const int t = bid % NT;
  const int b = bid / NT;
  int u = t, ti = 0;
  while (u >= 8 - ti) { u -= 8 - ti; ++ti; }
  const int tj = ti + u;
  const int brow = ti * 128;
  const int bcol = tj * 128;

  const int rtA0 = ti * 8 + wr * 4;   // A row-tiles (16 rows each)
  const int rtB0 = tj * 8 + wc * 4;   // B row-tiles (Gram columns)

  f32x4 acc[4][4];
  #pragma unroll
  for (int m = 0; m < 4; ++m)
    #pragma unroll
    for (int n = 0; n < 4; ++n) acc[m][n] = f32x4{0.f, 0.f, 0.f, 0.f};

  if (MODE == 0) {
    const unsigned short* pa =
        dbf2 + (((size_t)b * 8) * 64 + rtA0) * 512 + (size_t)lane * 8;
    const unsigned short* pb =
        dbf2 + (((size_t)b * 8) * 64 + rtB0) * 512 + (size_t)lane * 8;
    bf16x8 af[4], bf[4], nf[4];
    #pragma unroll
    for (int m = 0; m < 4; ++m)
      af[m] = *reinterpret_cast<const bf16x8*>(pa + m * 512);
    #pragma unroll
    for (int n = 0; n < 4; ++n)
      bf[n] = *reinterpret_cast<const bf16x8*>(pb + n * 512);
    #pragma unroll
    for (int kg = 0; kg < 8; ++kg) {
      if (kg < 7) {
        #pragma unroll
        for (int m = 0; m < 4; ++m)
          nf[m] = *reinterpret_cast<const bf16x8*>(pa + 32768 + m * 512);
      }
      #pragma unroll
      for (int n = 0; n < 4; ++n) {
        #pragma unroll
        for (int m = 0; m < 4; ++m)
          acc[m][n] = __builtin_amdgcn_mfma_f32_16x16x32_bf16(af[m], bf[n], acc[m][n], 0, 0, 0);
        if (kg < 7)
          bf[n] = *reinterpret_cast<const bf16x8*>(pb + 32768 + n * 512);  // bf[n] dead
      }
      if (kg < 7) {
        #pragma unroll
        for (int m = 0; m < 4; ++m) af[m] = nf[m];
        pa += 32768; pb += 32768;
      }
    }
  } else {
    const float* pbase = dvec + (size_t)b * NS * DD + (lane >> 4) * 8;
    #pragma unroll
    for (int kg = 0; kg < 8; ++kg) {
      bf16x8 af[4], bf[4];
      #pragma unroll
      for (int m = 0; m < 4; ++m) {
        const float* p = pbase + (size_t)((rtA0 + m) * 16 + (lane & 15)) * DD + kg * 32;
        float4 v0 = reinterpret_cast<const float4*>(p)[0];
        float4 v1 = reinterpret_cast<const float4*>(p)[1];
        af[m][0] = (short)f2bf(v0.x); af[m][1] = (short)f2bf(v0.y);
        af[m][2] = (short)f2bf(v0.z); af[m][3] = (short)f2bf(v0.w);
        af[m][4] = (short)f2bf(v1.x); af[m][5] = (short)f2bf(v1.y);
        af[m][6] = (short)f2bf(v1.z); af[m][7] = (short)f2bf(v1.w);
      }
      #pragma unroll
      for (int n = 0; n < 4; ++n) {
        const float* p = pbase + (size_t)((rtB0 + n) * 16 + (lane & 15)) * DD + kg * 32;
        float4 v0 = reinterpret_cast<const float4*>(p)[0];
        float4 v1 = reinterpret_cast<const float4*>(p)[1];
        bf[n][0] = (short)f2bf(v0.x); bf[n][1] = (short)f2bf(v0.y);
        bf[n][2] = (short)f2bf(v0.z); bf[n][3] = (short)f2bf(v0.w);
        bf[n][4] = (short)f2bf(v1.x); bf[n][5] = (short)f2bf(v1.y);
        bf[n][6] = (short)f2bf(v1.z); bf[n][7] = (short)f2bf(v1.w);
      }
      #pragma unroll
      for (int m = 0; m < 4; ++m)
        #pragma unroll
        for (int n = 0; n < 4; ++n)
          acc[m][n] = __builtin_amdgcn_mfma_f32_16x16x32_bf16(af[m], bf[n], acc[m][n], 0, 0, 0);
    }
  }

  // ---- epilogue, two-pass: branch-free d2 min scan; rare kd path under one
  // ballot. exp(-dist) is sub-f32-eps vs S once d2 > THR -> bit-identical. ----
  const float* sqb = sq + (size_t)b * NS;
  const int hi = lane >> 4, lo = lane & 15;
  float sqc[4];
  #pragma unroll
  for (int n = 0; n < 4; ++n) sqc[n] = sqb[bcol + wc * 64 + n * 16 + lo];
  float dmin = 1e30f;
  #pragma unroll
  for (int m = 0; m < 4; ++m) {
    #pragma unroll
    for (int j = 0; j < 4; ++j) {
      const int r = brow + wr * 64 + m * 16 + hi * 4 + j;
      const float sqr = sqb[r];
      #pragma unroll
      for (int n = 0; n < 4; ++n) {
        const int c = bcol + wc * 64 + n * 16 + lo;
        const float d2 = fmaxf(sqr + sqc[n] - 2.0f * acc[m][n][j], 0.0f);
        dmin = fminf(dmin, (r < c) ? d2 : 1e30f);
      }
    }
  }
  float wsum = 0.f;
  if (__any(dmin < THR)) {
    // pair (r,c), r<c: kd^2*(W[r][c]+W[c][r]) - 2*kd*(W[r][c]S[r][c]+W[c][r]S[c][r])
    float lsum = 0.f;
    #pragma unroll
    for (int m = 0; m < 4; ++m) {
      #pragma unroll
      for (int j = 0; j < 4; ++j) {
        const int r = brow + wr * 64 + m * 16 + hi * 4 + j;
        const float sqr = sqb[r];
        #pragma unroll
        for (int n = 0; n < 4; ++n) {
          const int c = bcol + wc * 64 + n * 16 + lo;
          const float d2 = fmaxf(sqr + sqc[n] - 2.0f * acc[m][n][j], 0.0f);
          if ((r < c) && (d2 < THR)) {
            const float kd = __expf(-sqrtf(d2));
            const float wrc = W[(size_t)r * NS + c];
            const float wcr = W[(size_t)c * NS + r];
            const float src_ = S[(size_t)r * NS + c];
            const float scr = S[(size_t)c * NS + r];
            lsum = fmaf(kd, kd * (wrc + wcr) - 2.0f * fmaf(wrc, src_, wcr * scr), lsum);
          }
        }
      }
    }
    #pragma unroll
    for (int off = 32; off > 0; off >>= 1) lsum += __shfl_xor(lsum, off, 64);
    wsum = lsum;
  }
  // unconditional per-(block,wave) partial (poison-safe, no atomics)
  if (lane == 0) npart[(size_t)bid * 4 + wid] = wsum;
}

// ---- final: npart[b*144 .. +144) per batch; out = sum_b 2*sqrt(C+n_b)/sqrt(D) ----
__global__ void final_kernel(const float* __restrict__ npart,
                             const float* __restrict__ dpart,
                             const float* __restrict__ cpart,
                             float* __restrict__ out) {
  const int lane = threadIdx.x;
  float dsum = 0.f, csum = 0.f;
  #pragma unroll
  for (int j = 0; j < 8; ++j) {
    dsum += dpart[lane + 64 * j];
    csum += cpart[lane + 64 * j];
  }
  #pragma unroll
  for (int off = 32; off > 0; off >>= 1) {
    dsum += __shfl_xor(dsum, off, 64);
    csum += __shfl_xor(csum, off, 64);
  }
  // lane b: reduce its batch's 36 tiles x 4 waves = 144 contiguous floats
  float nb = 0.f;
  const f32x4* np = reinterpret_cast<const f32x4*>(npart + (size_t)lane * 144);
  #pragma unroll
  for (int j = 0; j < 36; ++j) {
    f32x4 v = np[j];
    nb += v[0] + v[1] + v[2] + v[3];
  }
  float v = 2.0f * sqrtf(csum + nb);
  #pragma unroll
  for (int off = 32; off > 0; off >>= 1) v += __shfl_xor(v, off, 64);
  if (lane == 0) out[0] = v / sqrtf(dsum);
}

extern "C" void kernel_launch(void* const* d_in, const int* in_sizes, int n_in,
                              void* d_out, int out_size, void* d_ws, size_t ws_size,
                              hipStream_t stream) {
  const float* dvec = (const float*)d_in[0];
  const float* S = (const float*)d_in[1];
  const float* W = (const float*)d_in[2];
  float* out = (float*)d_out;

  const size_t bf_bytes = (size_t)NB * NS * DD * sizeof(unsigned short);  // 32 MiB
  const size_t sq_bytes = (size_t)NB * NS * sizeof(float);                // 256 KiB
  const size_t small_bytes = sq_bytes + (9216 + 512 + 512) * sizeof(float);
  const bool full = ws_size >= bf_bytes + small_bytes;

  unsigned short* dbf2;
  float* sqp;
  if (full) {
    dbf2 = (unsigned short*)d_ws;
    sqp = (float*)((char*)d_ws + bf_bytes);
  } else {
    dbf2 = nullptr;
    sqp = (float*)d_ws;
  }
  float* npart = sqp + (size_t)NB * NS;    // 9216 floats (2304 blocks x 4 waves)
  float* dpart = npart + 9216;             // 512
  float* cpart = dpart + 512;              // 512

  prep_kernel<<<1024 + 512, 256, 0, stream>>>(dvec, dbf2, sqp, S, W, dpart, cpart,
                                              full ? 1 : 0);
  if (full)
    main_kernel<0><<<NT * NB, 256, 0, stream>>>(dvec, dbf2, sqp, S, W, npart);
  else
    main_kernel<1><<<NT * NB, 256, 0, stream>>>(dvec, dbf2, sqp, S, W, npart);
  final_kernel<<<1, 64, 0, stream>>>(npart, dpart, cpart, out);
}

// Round 11
// 46.571 us; speedup vs baseline: 1.0562x; 1.0562x over previous
//
#include <hip/hip_runtime.h>
#include <hip/hip_bf16.h>

#define NB 64
#define NS 1024
#define DD 256
#define NT 36          // upper-triangular 8x8 tile count
#define THR 120.0f     // dist^2 below which exp(-dist) can matter

typedef __attribute__((ext_vector_type(4))) float f32x4;
typedef __attribute__((ext_vector_type(8))) short bf16x8;
typedef __attribute__((ext_vector_type(8))) unsigned short u16x8;
typedef __attribute__((ext_vector_type(4))) unsigned short u16x4;

__device__ __forceinline__ unsigned short f2bf(float x) {
  union { float f; unsigned int u; } c; c.f = x;
  unsigned int r = c.u + 0x7fffu + ((c.u >> 16) & 1u);
  return (unsigned short)(r >> 16);
}

// dbf2 layout (kg-major fragment blocks): block(b, kg, rt) = (b*8 + kg)*64 + rt,
// 512 bf16 each. Slot s (0..63) holds 8 bf16: row = rt*16 + (s&15),
// k = kg*32 + (s>>4)*8 + 0..7.

// ---- prep: 4096 blocks x 128 threads (2 waves). One 16-row tile per BLOCK:
//      wave w loads rows w*8..w*8+7 (coalesced 1KB f32 loads), exact-f32 sq
//      per row, XOR-swizzled LDS write; one barrier; wave w stores kg blocks
//      w*4..w*4+3 as full 64-lane 1KB coalesced fragment stores.
//      LDS = 8KB/block = 4KB/wave -> 16 blocks/CU -> 32 waves/CU (vs R9's 20).
//      XCD-matched: XCD k (= px&7) writes batches [8k,8k+8) = main's readers.
__global__ __launch_bounds__(128) void prep_kernel(const float* __restrict__ din,
                                                   unsigned short* __restrict__ dbf2,
                                                   float* __restrict__ sq,
                                                   int write_bf) {
  __shared__ unsigned short T[16][256];          // 8 KB, block-shared
  const int px = (int)blockIdx.x;
  const int wid = (int)threadIdx.x >> 6;         // 0,1
  const int l = (int)threadIdx.x & 63;
  // XCD k handles tb in [512k, 512k+512) -> b in [8k, 8k+8)
  const int tb = (px & 7) * 512 + (px >> 3);     // tile task 0..4095
  const int b = tb >> 6, rt = tb & 63;
  const float4* src =
      reinterpret_cast<const float4*>(din + ((size_t)b * NS + rt * 16) * DD) + l;
  // load phase: 8 rows per wave
  #pragma unroll
  for (int j = 0; j < 8; ++j) {
    const int ri = wid * 8 + j;                  // row within tile
    float4 v = src[ri * 64];                     // row stride 256 f = 64 float4
    float s = v.x * v.x + v.y * v.y + v.z * v.z + v.w * v.w;
    #pragma unroll
    for (int off = 32; off > 0; off >>= 1) s += __shfl_xor(s, off, 64);
    if (l == 0) sq[(size_t)b * NS + rt * 16 + ri] = s;
    if (write_bf) {
      // lane l holds 8B-granule d=l of row ri; LDS 16B-chunk (l>>1)^(ri&7)
      u16x4 o;
      o[0] = f2bf(v.x); o[1] = f2bf(v.y); o[2] = f2bf(v.z); o[3] = f2bf(v.w);
      const int cp = (l >> 1) ^ (ri & 7);
      *reinterpret_cast<u16x4*>(&T[ri][cp * 8 + (l & 1) * 4]) = o;
    }
  }
  if (!write_bf) return;
  __syncthreads();
  // store phase: wave w covers kg = w*4 + q; slot l = row (l&15), chunk
  // kg*4+(l>>4), stored at LDS chunk ^(l&7). 1KB coalesced store per kg.
  unsigned short* dst = dbf2 + (((size_t)b * 8) * 64 + rt) * 512 + (size_t)l * 8;
  #pragma unroll
  for (int q = 0; q < 4; ++q) {
    const int kg = wid * 4 + q;
    const int cc = (kg * 4 + (l >> 4)) ^ (l & 7);
    u16x8 frag = *reinterpret_cast<const u16x8*>(&T[l & 15][cc * 8]);
    *reinterpret_cast<u16x8*>(dst + (size_t)kg * 64 * 512) = frag;
  }
}

// ---- main: blocks [0, 2304): barrier-free LDS-free MFMA Gram (one batch,
// one upper-tri tile per block); blocks [2304, 2816): denom2/C partials
// (overlaps the MFMA work; independent of prep's output).
template <int MODE>
__global__ __launch_bounds__(256, 2) void main_kernel(
    const float* __restrict__ dvec, const unsigned short* __restrict__ dbf2,
    const float* __restrict__ sq, const float* __restrict__ S,
    const float* __restrict__ W, float* __restrict__ npart,
    float* __restrict__ dpart, float* __restrict__ cpart) {
  const int tid = threadIdx.x;
  const int lane = tid & 63;
  const int wid = tid >> 6;
  const int orig = (int)blockIdx.x;

  if (orig >= NT * NB) {
    // ---- denomC partials: blk in [0,512), 256 thr x 2 float4 each ----
    const int blk = orig - NT * NB;
    const int base = blk * 256 + tid;
    float dsum = 0.f, csum = 0.f;
    #pragma unroll
    for (int rpt = 0; rpt < 2; ++rpt) {
      const int idx = base + rpt * 131072;
      float4 w = reinterpret_cast<const float4*>(W)[idx];
      float4 s4 = reinterpret_cast<const float4*>(S)[idx];
      const int e0 = idx << 2;
      const int r = e0 >> 10, c0 = e0 & 1023;
      float wv[4] = {w.x, w.y, w.z, w.w};
      float sv[4] = {s4.x, s4.y, s4.z, s4.w};
      #pragma unroll
      for (int i = 0; i < 4; ++i) {
        const bool dg = (c0 + i) == r;
        const float a = wv[i] - (dg ? 1.0f : 0.0f);
        dsum = fmaf(a, a, dsum);
        const float bq = dg ? (1.0f - sv[i]) : sv[i];
        csum = fmaf(wv[i] * bq, bq, csum);   // W binary: W^2 == W
      }
    }
    #pragma unroll
    for (int off = 32; off > 0; off >>= 1) {
      dsum += __shfl_xor(dsum, off, 64);
      csum += __shfl_xor(csum, off, 64);
    }
    __shared__ float redD[4], redC[4];
    if (lane == 0) { redD[wid] = dsum; redC[wid] = csum; }
    __syncthreads();
    if (tid == 0) {
      dpart[blk] = redD[0] + redD[1] + redD[2] + redD[3];
      cpart[blk] = redC[0] + redC[1] + redC[2] + redC[3];
    }
    return;
  }

  const int wr = wid >> 1;
  const int wc = wid & 1;
  // XCD-chunked bijective swizzle (2304 = 8 * 288): XCD k gets bids
  // [288k, 288k+288) -> b in [8k, 8k+8) (t-fast) = the batches its L2 holds.
  const int bid = (orig & 7) * (NT * NB / 8) + (orig >> 3);
  const int t = bid % NT;
  const int b = bid / NT;
  int u = t, ti = 0;
  while (u >= 8 - ti) { u -= 8 - ti; ++ti; }
  const int tj = ti + u;
  const int brow = ti * 128;
  const int bcol = tj * 128;

  const int rtA0 = ti * 8 + wr * 4;   // A row-tiles (16 rows each)
  const int rtB0 = tj * 8 + wc * 4;   // B row-tiles (Gram columns)

  f32x4 acc[4][4];
  #pragma unroll
  for (int m = 0; m < 4; ++m)
    #pragma unroll
    for (int n = 0; n < 4; ++n) acc[m][n] = f32x4{0.f, 0.f, 0.f, 0.f};

  if (MODE == 0) {
    const unsigned short* pa =
        dbf2 + (((size_t)b * 8) * 64 + rtA0) * 512 + (size_t)lane * 8;
    const unsigned short* pb =
        dbf2 + (((size_t)b * 8) * 64 + rtB0) * 512 + (size_t)lane * 8;
    bf16x8 af[4], bf[4], nf[4];
    #pragma unroll
    for (int m = 0; m < 4; ++m)
      af[m] = *reinterpret_cast<const bf16x8*>(pa + m * 512);
    #pragma unroll
    for (int n = 0; n < 4; ++n)
      bf[n] = *reinterpret_cast<const bf16x8*>(pb + n * 512);
    #pragma unroll
    for (int kg = 0; kg < 8; ++kg) {
      if (kg < 7) {
        #pragma unroll
        for (int m = 0; m < 4; ++m)
          nf[m] = *reinterpret_cast<const bf16x8*>(pa + 32768 + m * 512);
      }
      #pragma unroll
      for (int n = 0; n < 4; ++n) {
        #pragma unroll
        for (int m = 0; m < 4; ++m)
          acc[m][n] = __builtin_amdgcn_mfma_f32_16x16x32_bf16(af[m], bf[n], acc[m][n], 0, 0, 0);
        if (kg < 7)
          bf[n] = *reinterpret_cast<const bf16x8*>(pb + 32768 + n * 512);  // bf[n] dead
      }
      if (kg < 7) {
        #pragma unroll
        for (int m = 0; m < 4; ++m) af[m] = nf[m];
        pa += 32768; pb += 32768;
      }
    }
  } else {
    const float* pbase = dvec + (size_t)b * NS * DD + (lane >> 4) * 8;
    #pragma unroll
    for (int kg = 0; kg < 8; ++kg) {
      bf16x8 af[4], bf[4];
      #pragma unroll
      for (int m = 0; m < 4; ++m) {
        const float* p = pbase + (size_t)((rtA0 + m) * 16 + (lane & 15)) * DD + kg * 32;
        float4 v0 = reinterpret_cast<const float4*>(p)[0];
        float4 v1 = reinterpret_cast<const float4*>(p)[1];
        af[m][0] = (short)f2bf(v0.x); af[m][1] = (short)f2bf(v0.y);
        af[m][2] = (short)f2bf(v0.z); af[m][3] = (short)f2bf(v0.w);
        af[m][4] = (short)f2bf(v1.x); af[m][5] = (short)f2bf(v1.y);
        af[m][6] = (short)f2bf(v1.z); af[m][7] = (short)f2bf(v1.w);
      }
      #pragma unroll
      for (int n = 0; n < 4; ++n) {
        const float* p = pbase + (size_t)((rtB0 + n) * 16 + (lane & 15)) * DD + kg * 32;
        float4 v0 = reinterpret_cast<const float4*>(p)[0];
        float4 v1 = reinterpret_cast<const float4*>(p)[1];
        bf[n][0] = (short)f2bf(v0.x); bf[n][1] = (short)f2bf(v0.y);
        bf[n][2] = (short)f2bf(v0.z); bf[n][3] = (short)f2bf(v0.w);
        bf[n][4] = (short)f2bf(v1.x); bf[n][5] = (short)f2bf(v1.y);
        bf[n][6] = (short)f2bf(v1.z); bf[n][7] = (short)f2bf(v1.w);
      }
      #pragma unroll
      for (int m = 0; m < 4; ++m)
        #pragma unroll
        for (int n = 0; n < 4; ++n)
          acc[m][n] = __builtin_amdgcn_mfma_f32_16x16x32_bf16(af[m], bf[n], acc[m][n], 0, 0, 0);
    }
  }

  // ---- epilogue, two-pass: branch-free d2 min scan; rare kd path under one
  // ballot. exp(-dist) is sub-f32-eps vs S once d2 > THR -> bit-identical. ----
  const float* sqb = sq + (size_t)b * NS;
  const int hi = lane >> 4, lo = lane & 15;
  float sqc[4];
  #pragma unroll
  for (int n = 0; n < 4; ++n) sqc[n] = sqb[bcol + wc * 64 + n * 16 + lo];
  float dmin = 1e30f;
  #pragma unroll
  for (int m = 0; m < 4; ++m) {
    #pragma unroll
    for (int j = 0; j < 4; ++j) {
      const int r = brow + wr * 64 + m * 16 + hi * 4 + j;
      const float sqr = sqb[r];
      #pragma unroll
      for (int n = 0; n < 4; ++n) {
        const int c = bcol + wc * 64 + n * 16 + lo;
        const float d2 = fmaxf(sqr + sqc[n] - 2.0f * acc[m][n][j], 0.0f);
        dmin = fminf(dmin, (r < c) ? d2 : 1e30f);
      }
    }
  }
  float wsum = 0.f;
  if (__any(dmin < THR)) {
    // pair (r,c), r<c: kd^2*(W[r][c]+W[c][r]) - 2*kd*(W[r][c]S[r][c]+W[c][r]S[c][r])
    float lsum = 0.f;
    #pragma unroll
    for (int m = 0; m < 4; ++m) {
      #pragma unroll
      for (int j = 0; j < 4; ++j) {
        const int r = brow + wr * 64 + m * 16 + hi * 4 + j;
        const float sqr = sqb[r];
        #pragma unroll
        for (int n = 0; n < 4; ++n) {
          const int c = bcol + wc * 64 + n * 16 + lo;
          const float d2 = fmaxf(sqr + sqc[n] - 2.0f * acc[m][n][j], 0.0f);
          if ((r < c) && (d2 < THR)) {
            const float kd = __expf(-sqrtf(d2));
            const float wrc = W[(size_t)r * NS + c];
            const float wcr = W[(size_t)c * NS + r];
            const float src_ = S[(size_t)r * NS + c];
            const float scr = S[(size_t)c * NS + r];
            lsum = fmaf(kd, kd * (wrc + wcr) - 2.0f * fmaf(wrc, src_, wcr * scr), lsum);
          }
        }
      }
    }
    #pragma unroll
    for (int off = 32; off > 0; off >>= 1) lsum += __shfl_xor(lsum, off, 64);
    wsum = lsum;
  }
  // unconditional per-(block,wave) partial (poison-safe, no atomics)
  if (lane == 0) npart[(size_t)bid * 4 + wid] = wsum;
}

// ---- final: npart[b*144 .. +144) per batch; out = sum_b 2*sqrt(C+n_b)/sqrt(D) ----
__global__ void final_kernel(const float* __restrict__ npart,
                             const float* __restrict__ dpart,
                             const float* __restrict__ cpart,
                             float* __restrict__ out) {
  const int lane = threadIdx.x;
  float dsum = 0.f, csum = 0.f;
  #pragma unroll
  for (int j = 0; j < 8; ++j) {
    dsum += dpart[lane + 64 * j];
    csum += cpart[lane + 64 * j];
  }
  #pragma unroll
  for (int off = 32; off > 0; off >>= 1) {
    dsum += __shfl_xor(dsum, off, 64);
    csum += __shfl_xor(csum, off, 64);
  }
  // lane b: reduce its batch's 36 tiles x 4 waves = 144 contiguous floats
  float nb = 0.f;
  const f32x4* np = reinterpret_cast<const f32x4*>(npart + (size_t)lane * 144);
  #pragma unroll
  for (int j = 0; j < 36; ++j) {
    f32x4 v = np[j];
    nb += v[0] + v[1] + v[2] + v[3];
  }
  float v = 2.0f * sqrtf(csum + nb);
  #pragma unroll
  for (int off = 32; off > 0; off >>= 1) v += __shfl_xor(v, off, 64);
  if (lane == 0) out[0] = v / sqrtf(dsum);
}

extern "C" void kernel_launch(void* const* d_in, const int* in_sizes, int n_in,
                              void* d_out, int out_size, void* d_ws, size_t ws_size,
                              hipStream_t stream) {
  const float* dvec = (const float*)d_in[0];
  const float* S = (const float*)d_in[1];
  const float* W = (const float*)d_in[2];
  float* out = (float*)d_out;

  const size_t bf_bytes = (size_t)NB * NS * DD * sizeof(unsigned short);  // 32 MiB
  const size_t sq_bytes = (size_t)NB * NS * sizeof(float);                // 256 KiB
  const size_t small_bytes = sq_bytes + (9216 + 512 + 512) * sizeof(float);
  const bool full = ws_size >= bf_bytes + small_bytes;

  unsigned short* dbf2;
  float* sqp;
  if (full) {
    dbf2 = (unsigned short*)d_ws;
    sqp = (float*)((char*)d_ws + bf_bytes);
  } else {
    dbf2 = nullptr;
    sqp = (float*)d_ws;
  }
  float* npart = sqp + (size_t)NB * NS;    // 9216 floats (2304 blocks x 4 waves)
  float* dpart = npart + 9216;             // 512
  float* cpart = dpart + 512;              // 512

  prep_kernel<<<4096, 128, 0, stream>>>(dvec, dbf2, sqp, full ? 1 : 0);
  if (full)
    main_kernel<0><<<NT * NB + 512, 256, 0, stream>>>(dvec, dbf2, sqp, S, W,
                                                      npart, dpart, cpart);
  else
    main_kernel<1><<<NT * NB + 512, 256, 0, stream>>>(dvec, dbf2, sqp, S, W,
                                                      npart, dpart, cpart);
  final_kernel<<<1, 64, 0, stream>>>(npart, dpart, cpart, out);
}